// Round 4
// baseline (847.617 us; speedup 1.0000x reference)
//
#include <hip/hip_runtime.h>
#include <stdint.h>

#define DIMS 256
#define NT 4096
#define NROWS 65536
#define THETA 1.5e-4f

typedef float    f32x4_t __attribute__((ext_vector_type(4)));
typedef _Float16 f16x8_t __attribute__((ext_vector_type(8)));
typedef _Float16 f16x4_t __attribute__((ext_vector_type(4)));

// top-2 insert with jnp.argmin tie-break (lowest index wins on equal value)
__device__ __forceinline__ void t2ins(float v, int i, float& v1, int& i1, float& v2, int& i2){
  if (v < v1 || (v == v1 && i < i1)) { v2 = v1; i2 = i1; v1 = v; i1 = i; }
  else if (v < v2 || (v == v2 && i < i2)) { v2 = v; i2 = i; }
}

// ---- kernel 0a: sx[n] = np.sum(flat*flat, axis=1) bit-exact (pairwise 256 = P128 + P128) ----
__global__ void vq_sx(const float* __restrict__ x, float* __restrict__ sx){
  const int n = blockIdx.x * 64 + threadIdx.x;
  const int b = n >> 12, t = n & 4095;
  const float* xp = x + (size_t)b * DIMS * NT + t;
  float half[2];
  #pragma unroll
  for (int h = 0; h < 2; ++h){
    float r[8];
    #pragma unroll
    for (int j = 0; j < 8; ++j){
      float v = xp[(size_t)(h*128 + j) * NT];
      r[j] = __fmul_rn(v, v);
    }
    for (int i = 8; i < 128; i += 8){
      #pragma unroll
      for (int j = 0; j < 8; ++j){
        float v = xp[(size_t)(h*128 + i + j) * NT];
        r[j] = __fadd_rn(r[j], __fmul_rn(v, v));
      }
    }
    half[h] = __fadd_rn(__fadd_rn(__fadd_rn(r[0], r[1]), __fadd_rn(r[2], r[3])),
                        __fadd_rn(__fadd_rn(r[4], r[5]), __fadd_rn(r[6], r[7])));
  }
  sx[n] = __fadd_rn(half[0], half[1]);
}

// ---- kernel 0b: se[k] = np.sum(cb*cb, axis=1) bit-exact ----
__global__ void vq_se(const float* __restrict__ cb, float* __restrict__ se){
  const int k = blockIdx.x * 64 + threadIdx.x;
  const float* ep = cb + (size_t)k * DIMS;
  float half[2];
  #pragma unroll
  for (int h = 0; h < 2; ++h){
    float r[8];
    #pragma unroll
    for (int j = 0; j < 8; ++j){
      float v = ep[h*128 + j];
      r[j] = __fmul_rn(v, v);
    }
    for (int i = 8; i < 128; i += 8){
      #pragma unroll
      for (int j = 0; j < 8; ++j){
        float v = ep[h*128 + i + j];
        r[j] = __fadd_rn(r[j], __fmul_rn(v, v));
      }
    }
    half[h] = __fadd_rn(__fadd_rn(__fadd_rn(r[0], r[1]), __fadd_rn(r[2], r[3])),
                        __fadd_rn(__fadd_rn(r[4], r[5]), __fadd_rn(r[6], r[7])));
  }
  se[k] = __fadd_rn(half[0], half[1]);
}

// ---- kernel 1: approx scores via single-pass fp16 MFMA + fused per-row top-2 ----
// tile: 128 rows (t) x 128 codes, contraction 256 in 8 chunks of 32.
// B is scaled by 512 (exact pow2); score = se_k - dot/256.
__global__ __launch_bounds__(256) void vq_scores(
    const float* __restrict__ x, const float* __restrict__ cb,
    const float* __restrict__ se, float4* __restrict__ partials)
{
  __shared__ _Float16 Ah[128][40];
  __shared__ _Float16 Bh[128][40];
  __shared__ float4 comb[128][2];

  const int tid  = threadIdx.x;
  const int lane = tid & 63;
  const int wid  = tid >> 6;
  const int wr   = wid >> 1;      // wave row 0..1 (64 rows each)
  const int wc   = wid & 1;       // wave col 0..1 (64 codes each)
  const int kt   = blockIdx.x;    // 0..7 code tile
  const int rt   = blockIdx.y;    // 0..511 row tile
  const int bb   = rt >> 5;
  const int t0   = (rt & 31) << 7;
  const int k0   = kt << 7;

  const int c4    = tid & 7;                 // channel quad for A staging
  const int tt    = ((tid >> 3) & 31) << 2;  // t offset for A staging
  const int codeS = tid >> 1;                // code row for B staging
  const int cbOff = (tid & 1) << 4;          // c offset (0/16) for B staging

  const int fr = lane & 15;
  const int fq = lane >> 4;

  f32x4_t acc[4][4];
  #pragma unroll
  for (int a = 0; a < 4; ++a)
    #pragma unroll
    for (int q = 0; q < 4; ++q){
      f32x4_t z = {0.f, 0.f, 0.f, 0.f};
      acc[a][q] = z;
    }

  for (int cc = 0; cc < 8; ++cc){
    const int c0 = cc << 5;
    const float* xp = x + ((size_t)(bb*DIMS + c0 + c4*4))*NT + t0 + tt;
    float4 va0 = *(const float4*)(xp);
    float4 va1 = *(const float4*)(xp + NT);
    float4 va2 = *(const float4*)(xp + 2*NT);
    float4 va3 = *(const float4*)(xp + 3*NT);
    const float* cp = cb + (size_t)(k0 + codeS)*DIMS + c0 + cbOff;
    float4 vb0 = *(const float4*)(cp);
    float4 vb1 = *(const float4*)(cp + 4);
    float4 vb2 = *(const float4*)(cp + 8);
    float4 vb3 = *(const float4*)(cp + 12);

    __syncthreads();  // prior iteration's LDS reads done

    #pragma unroll
    for (int j = 0; j < 4; ++j){
      f16x4_t p;
      p.x = (_Float16)((&va0.x)[j]);
      p.y = (_Float16)((&va1.x)[j]);
      p.z = (_Float16)((&va2.x)[j]);
      p.w = (_Float16)((&va3.x)[j]);
      *(f16x4_t*)&Ah[tt + j][c4*4] = p;
    }
    {
      f16x4_t p;
      p.x=(_Float16)(vb0.x*512.f); p.y=(_Float16)(vb0.y*512.f);
      p.z=(_Float16)(vb0.z*512.f); p.w=(_Float16)(vb0.w*512.f);
      *(f16x4_t*)&Bh[codeS][cbOff + 0] = p;
      p.x=(_Float16)(vb1.x*512.f); p.y=(_Float16)(vb1.y*512.f);
      p.z=(_Float16)(vb1.z*512.f); p.w=(_Float16)(vb1.w*512.f);
      *(f16x4_t*)&Bh[codeS][cbOff + 4] = p;
      p.x=(_Float16)(vb2.x*512.f); p.y=(_Float16)(vb2.y*512.f);
      p.z=(_Float16)(vb2.z*512.f); p.w=(_Float16)(vb2.w*512.f);
      *(f16x4_t*)&Bh[codeS][cbOff + 8] = p;
      p.x=(_Float16)(vb3.x*512.f); p.y=(_Float16)(vb3.y*512.f);
      p.z=(_Float16)(vb3.z*512.f); p.w=(_Float16)(vb3.w*512.f);
      *(f16x4_t*)&Bh[codeS][cbOff + 12] = p;
    }

    __syncthreads();

    f16x8_t ahf[4], bhf[4];
    #pragma unroll
    for (int mf = 0; mf < 4; ++mf)
      ahf[mf] = *(const f16x8_t*)&Ah[wr*64 + mf*16 + fr][fq*8];
    #pragma unroll
    for (int cf = 0; cf < 4; ++cf)
      bhf[cf] = *(const f16x8_t*)&Bh[wc*64 + cf*16 + fr][fq*8];
    #pragma unroll
    for (int mf = 0; mf < 4; ++mf)
      #pragma unroll
      for (int cf = 0; cf < 4; ++cf)
        acc[mf][cf] = __builtin_amdgcn_mfma_f32_16x16x32_f16(ahf[mf], bhf[cf], acc[mf][cf], 0, 0, 0);
  }

  // epilogue: score = se_k - dot/256 ; per-row top-2 over this block's 128 codes
  float sev[4];
  #pragma unroll
  for (int cf = 0; cf < 4; ++cf) sev[cf] = se[k0 + wc*64 + cf*16 + fr];

  #pragma unroll
  for (int mf = 0; mf < 4; ++mf){
    #pragma unroll
    for (int rg = 0; rg < 4; ++rg){
      float v1 = 3.4e38f, v2 = 3.4e38f;
      int   i1 = 0x7fffffff, i2 = 0x7fffffff;
      #pragma unroll
      for (int cf = 0; cf < 4; ++cf){
        float v = fmaf(acc[mf][cf][rg], -1.0f/256.0f, sev[cf]);
        int  ci = k0 + wc*64 + cf*16 + fr;
        t2ins(v, ci, v1, i1, v2, i2);
      }
      #pragma unroll
      for (int m = 1; m < 16; m <<= 1){
        float ov1 = __shfl_xor(v1, m);
        int   oi1 = __shfl_xor(i1, m);
        float ov2 = __shfl_xor(v2, m);
        int   oi2 = __shfl_xor(i2, m);
        t2ins(ov1, oi1, v1, i1, v2, i2);
        t2ins(ov2, oi2, v1, i1, v2, i2);
      }
      if (fr == 0){
        comb[wr*64 + mf*16 + fq*4 + rg][wc] =
            make_float4(v1, __int_as_float(i1), v2, __int_as_float(i2));
      }
    }
  }
  __syncthreads();
  if (tid < 128){
    float4 p0 = comb[tid][0];
    float4 p1 = comb[tid][1];
    float v1 = p0.x; int i1 = __float_as_int(p0.y);
    float v2 = p0.z; int i2 = __float_as_int(p0.w);
    t2ins(p1.x, __float_as_int(p1.y), v1, i1, v2, i2);
    t2ins(p1.z, __float_as_int(p1.w), v1, i1, v2, i2);
    partials[(size_t)(rt*128 + tid)*8 + kt] =
        make_float4(v1, __int_as_float(i1), v2, __int_as_float(i2));
  }
}

// ---- kernel 2: merge 8 partials per row; flag rows with margin < THETA (NaN-safe) ----
__global__ __launch_bounds__(256) void vq_merge(
    const float4* __restrict__ partials, int* __restrict__ idx,
    float* __restrict__ out2, unsigned* __restrict__ wl, unsigned* __restrict__ cnt)
{
  const int r = blockIdx.x * 256 + threadIdx.x;
  float v1 = 3.4e38f, v2 = 3.4e38f;
  int   i1 = 0x7fffffff, i2 = 0x7fffffff;
  #pragma unroll
  for (int kt = 0; kt < 8; ++kt){
    float4 p = partials[(size_t)r*8 + kt];
    t2ins(p.x, __float_as_int(p.y), v1, i1, v2, i2);
    t2ins(p.z, __float_as_int(p.w), v1, i1, v2, i2);
  }
  idx[r]  = i1;
  out2[r] = (float)i1;
  if (!(v2 - v1 >= THETA)){
    unsigned pos = atomicAdd(cnt, 1u);
    wl[pos] = (unsigned)r;
  }
}

// ---- kernel 3: exact fp32-numpy-emulated full re-scan of flagged rows (8 rows/block) ----
__global__ __launch_bounds__(256) void vq_refine(
    const float* __restrict__ x, const float* __restrict__ cb,
    const float* __restrict__ sx, const float* __restrict__ se,
    const unsigned* __restrict__ wl, const unsigned* __restrict__ cnt,
    int* __restrict__ idx, float* __restrict__ out2)
{
  __shared__ float eT[8][1024];   // 32 KiB transposed codebook chunk
  __shared__ float xs[DIMS][8];   // 8 KiB
  __shared__ int   rows_s[8];
  __shared__ float sxs[8];
  __shared__ float wv[4][8];
  __shared__ int   wi[4][8];

  const unsigned n = *cnt;
  const unsigned groups = (n + 7u) >> 3;
  const int tid  = threadIdx.x;
  const int lane = tid & 63;
  const int wid  = tid >> 6;

  for (unsigned g = blockIdx.x; g < groups; g += gridDim.x){
    __syncthreads();   // protect rows_s/xs/wv reuse across groups
    if (tid < 8){
      unsigned e = g*8u + (unsigned)tid;
      int row = (int)wl[e < n ? e : (n - 1u)];
      rows_s[tid] = row;
      sxs[tid] = sx[row];
    }
    __syncthreads();
    // stage x rows (scattered gather along c)
    #pragma unroll
    for (int rep = 0; rep < 8; ++rep){
      int id = rep * 256 + tid;
      int c = id >> 3, r = id & 7;
      int row = rows_s[r];
      int b = row >> 12, t = row & 4095;
      xs[c][r] = x[((size_t)(b*DIMS + c))*NT + t];
    }

    float s[8][4];
    #pragma unroll
    for (int r = 0; r < 8; ++r)
      #pragma unroll
      for (int u = 0; u < 4; ++u) s[r][u] = 0.f;

    for (int c0 = 0; c0 < DIMS; c0 += 8){
      __syncthreads();
      #pragma unroll
      for (int rep = 0; rep < 8; ++rep){
        int id2 = rep * 256 + tid;
        int k = id2 >> 1, q = id2 & 1;
        float4 v = *(const float4*)&cb[(size_t)k * DIMS + c0 + q * 4];
        eT[q*4 + 0][k] = v.x; eT[q*4 + 1][k] = v.y;
        eT[q*4 + 2][k] = v.z; eT[q*4 + 3][k] = v.w;
      }
      __syncthreads();
      #pragma unroll
      for (int cc = 0; cc < 8; ++cc){
        float4 ev = *(const float4*)&eT[cc][wid*256 + lane*4];
        #pragma unroll
        for (int r = 0; r < 8; ++r){
          float xv = xs[c0 + cc][r];
          s[r][0] = fmaf(xv, ev.x, s[r][0]);
          s[r][1] = fmaf(xv, ev.y, s[r][1]);
          s[r][2] = fmaf(xv, ev.z, s[r][2]);
          s[r][3] = fmaf(xv, ev.w, s[r][3]);
        }
      }
    }

    float4 sek = *(const float4*)&se[wid*256 + lane*4];
    #pragma unroll
    for (int r = 0; r < 8; ++r){
      const float sxv = sxs[r];
      float bv = 3.4e38f; int bi = 0x7fffffff;
      #pragma unroll
      for (int u = 0; u < 4; ++u){
        float d = __fsub_rn(__fadd_rn(sxv, (&sek.x)[u]),
                            __fadd_rn(s[r][u], s[r][u]));
        int k = wid*256 + lane*4 + u;
        if (d < bv || (d == bv && k < bi)) { bv = d; bi = k; }
      }
      #pragma unroll
      for (int m = 1; m < 64; m <<= 1){
        float ov = __shfl_xor(bv, m);
        int   oi = __shfl_xor(bi, m);
        if (ov < bv || (ov == bv && oi < bi)) { bv = ov; bi = oi; }
      }
      if (lane == 0){ wv[wid][r] = bv; wi[wid][r] = bi; }
    }
    __syncthreads();
    if (tid < 8){
      const int r = tid;
      float bv = wv[0][r]; int bi = wi[0][r];
      #pragma unroll
      for (int w = 1; w < 4; ++w){
        float ov = wv[w][r]; int oi = wi[w][r];
        if (ov < bv || (ov == bv && oi < bi)) { bv = ov; bi = oi; }
      }
      if (g*8u + (unsigned)r < n){
        int row = rows_s[r];
        idx[row]  = bi;
        out2[row] = (float)bi;
      }
    }
  }
}

// ---- kernel 4: gather quantized (== quantized_st), accumulate loss ----
__global__ __launch_bounds__(256) void vq_gather(
    const float* __restrict__ x, const float* __restrict__ cb,
    const int* __restrict__ idx, float* __restrict__ out0, double* __restrict__ acc)
{
  const int bc = blockIdx.x;          // b*256 + c
  const int bb = bc >> 8;
  const int c  = bc & 255;
  const float* xr = x + (size_t)bc * NT;
  float* orow = out0 + (size_t)bc * NT;
  const int* ir = idx + bb * NT;
  float s = 0.f;
  #pragma unroll
  for (int j = 0; j < 4; ++j){
    const int t = (threadIdx.x << 2) + (j << 10);
    float4 xv = *(const float4*)(xr + t);
    int4  iv  = *(const int4*)(ir + t);
    float4 q;
    q.x = cb[iv.x * DIMS + c];
    q.y = cb[iv.y * DIMS + c];
    q.z = cb[iv.z * DIMS + c];
    q.w = cb[iv.w * DIMS + c];
    float dx = q.x - xv.x, dy = q.y - xv.y, dz = q.z - xv.z, dw = q.w - xv.w;
    s += dx*dx + dy*dy + dz*dz + dw*dw;
    *(float4*)(orow + t) = q;
  }
  #pragma unroll
  for (int m = 1; m < 64; m <<= 1) s += __shfl_xor(s, m);
  __shared__ float wsum[4];
  if ((threadIdx.x & 63) == 0) wsum[threadIdx.x >> 6] = s;
  __syncthreads();
  if (threadIdx.x == 0){
    double tot = (double)wsum[0] + (double)wsum[1] + (double)wsum[2] + (double)wsum[3];
    atomicAdd(acc, tot);
  }
}

__global__ void vq_final(const double* __restrict__ acc, float* __restrict__ out1){
  *out1 = (float)(1.25 * (*acc) * (1.0 / 16777216.0));
}

extern "C" void kernel_launch(void* const* d_in, const int* in_sizes, int n_in,
                              void* d_out, int out_size, void* d_ws, size_t ws_size,
                              hipStream_t stream)
{
  const float* x  = (const float*)d_in[0];
  const float* cb = (const float*)d_in[1];
  float* out  = (float*)d_out;
  float* out0 = out;
  float* out1 = out + (size_t)16777216;   // vq_loss
  float* out2 = out + (size_t)16777217;   // indices as float [65536]

  char* ws = (char*)d_ws;
  double*   acc = (double*)(ws + 0);
  unsigned* cnt = (unsigned*)(ws + 8);
  float*    se  = (float*)(ws + 64);       // 4 KiB
  float*    sx  = (float*)(ws + 4160);     // 256 KiB
  int*      idx = (int*)(ws + 266304);     // 256 KiB

  // scratch in d_out region, consumed before vq_gather overwrites it:
  float4*   partials = (float4*)d_out;                       // 8 MiB
  unsigned* wl = (unsigned*)(out + (size_t)4*1024*1024);     // at 16 MiB, 256 KiB

  hipMemsetAsync(d_ws, 0, 16, stream);     // zero loss accumulator + worklist count
  vq_sx    <<<dim3(1024),   dim3(64),  0, stream>>>(x, sx);
  vq_se    <<<dim3(16),     dim3(64),  0, stream>>>(cb, se);
  vq_scores<<<dim3(8, 512), dim3(256), 0, stream>>>(x, cb, se, partials);
  vq_merge <<<dim3(256),    dim3(256), 0, stream>>>(partials, idx, out2, wl, cnt);
  vq_refine<<<dim3(512),    dim3(256), 0, stream>>>(x, cb, sx, se, wl, cnt, idx, out2);
  vq_gather<<<dim3(4096),   dim3(256), 0, stream>>>(x, cb, idx, out0, acc);
  vq_final <<<dim3(1),      dim3(1),   0, stream>>>(acc, out1);
}

// Round 5
// 776.566 us; speedup vs baseline: 1.0915x; 1.0915x over previous
//
#include <hip/hip_runtime.h>
#include <stdint.h>

#define DIMS 256
#define NT 4096
#define NROWS 65536
#define THETA 1.5e-4f

typedef float    f32x4_t __attribute__((ext_vector_type(4)));
typedef _Float16 f16x8_t __attribute__((ext_vector_type(8)));
typedef _Float16 f16x4_t __attribute__((ext_vector_type(4)));

// top-2 insert with jnp.argmin tie-break (lowest index wins on equal value)
__device__ __forceinline__ void t2ins(float v, int i, float& v1, int& i1, float& v2, int& i2){
  if (v < v1 || (v == v1 && i < i1)) { v2 = v1; i2 = i1; v1 = v; i1 = i; }
  else if (v < v2 || (v == v2 && i < i2)) { v2 = v; i2 = i; }
}

// ---- kernel 0a: sx[n] = np.sum(flat*flat, axis=1) bit-exact (pairwise 256 = P128 + P128) ----
__global__ __launch_bounds__(256) void vq_sx(const float* __restrict__ x, float* __restrict__ sx){
  const int n = blockIdx.x * 256 + threadIdx.x;
  const int b = n >> 12, t = n & 4095;
  const float* xp = x + (size_t)b * DIMS * NT + t;
  float half[2];
  #pragma unroll
  for (int h = 0; h < 2; ++h){
    float r[8];
    #pragma unroll
    for (int j = 0; j < 8; ++j){
      float v = xp[(size_t)(h*128 + j) * NT];
      r[j] = __fmul_rn(v, v);
    }
    for (int i = 8; i < 128; i += 8){
      #pragma unroll
      for (int j = 0; j < 8; ++j){
        float v = xp[(size_t)(h*128 + i + j) * NT];
        r[j] = __fadd_rn(r[j], __fmul_rn(v, v));
      }
    }
    half[h] = __fadd_rn(__fadd_rn(__fadd_rn(r[0], r[1]), __fadd_rn(r[2], r[3])),
                        __fadd_rn(__fadd_rn(r[4], r[5]), __fadd_rn(r[6], r[7])));
  }
  sx[n] = __fadd_rn(half[0], half[1]);
}

// ---- kernel 0b: se[k] = np.sum(cb*cb, axis=1) bit-exact ----
__global__ void vq_se(const float* __restrict__ cb, float* __restrict__ se){
  const int k = blockIdx.x * 64 + threadIdx.x;
  const float* ep = cb + (size_t)k * DIMS;
  float half[2];
  #pragma unroll
  for (int h = 0; h < 2; ++h){
    float r[8];
    #pragma unroll
    for (int j = 0; j < 8; ++j){
      float v = ep[h*128 + j];
      r[j] = __fmul_rn(v, v);
    }
    for (int i = 8; i < 128; i += 8){
      #pragma unroll
      for (int j = 0; j < 8; ++j){
        float v = ep[h*128 + i + j];
        r[j] = __fadd_rn(r[j], __fmul_rn(v, v));
      }
    }
    half[h] = __fadd_rn(__fadd_rn(__fadd_rn(r[0], r[1]), __fadd_rn(r[2], r[3])),
                        __fadd_rn(__fadd_rn(r[4], r[5]), __fadd_rn(r[6], r[7])));
  }
  se[k] = __fadd_rn(half[0], half[1]);
}

// ---- kernel 1: approx scores, 64 rows/block x ALL 1024 codes, fused top-2 ----
// A (x tile) staged once in LDS fp16; B double-buffered 8KB chunks; score = se_k - dot/256.
__global__ __launch_bounds__(256) void vq_scores(
    const float* __restrict__ x, const float* __restrict__ cb,
    const float* __restrict__ se, int* __restrict__ idx, float* __restrict__ out2,
    unsigned* __restrict__ wl, unsigned* __restrict__ cnt)
{
  __shared__ _Float16 Ah[64][264];        // 33792 B, row stride 132 dw === 4 (mod 32)
  __shared__ _Float16 Bh[2][128][40];     // 20480 B
  __shared__ float4   comb[64][4];        //  4096 B

  const int tid  = threadIdx.x;
  const int lane = tid & 63;
  const int wc   = tid >> 6;              // wave -> code quarter (32 codes per kt tile)
  const int fr   = lane & 15;
  const int fq   = lane >> 4;
  const int n0   = blockIdx.x * 64;
  const int bb   = n0 >> 12;
  const int t0   = n0 & 4095;

  // ---- stage A once: 64 rows x 256 c, fp16 ----
  {
    const int dup = tid >> 7;                 // 0..1 -> c chunks 0-3 / 4-7
    const int c4  = tid & 7;                  // c quad within chunk
    const int tt  = ((tid >> 3) & 15) << 2;   // 4-row group
    #pragma unroll
    for (int cc2 = 0; cc2 < 4; ++cc2){
      const int c0 = (dup*4 + cc2) * 32;
      const float* xp = x + ((size_t)(bb*DIMS + c0 + c4*4))*NT + t0 + tt;
      float4 va0 = *(const float4*)(xp);
      float4 va1 = *(const float4*)(xp + NT);
      float4 va2 = *(const float4*)(xp + 2*NT);
      float4 va3 = *(const float4*)(xp + 3*NT);
      #pragma unroll
      for (int j = 0; j < 4; ++j){
        f16x4_t p;
        p.x = (_Float16)((&va0.x)[j]);
        p.y = (_Float16)((&va1.x)[j]);
        p.z = (_Float16)((&va2.x)[j]);
        p.w = (_Float16)((&va3.x)[j]);
        *(f16x4_t*)&Ah[tt + j][c0 + c4*4] = p;
      }
    }
  }

  // per-thread running top-2 state per (mf, rg)
  float sv1[4][4], sv2[4][4];
  int   si1[4][4], si2[4][4];
  #pragma unroll
  for (int mf = 0; mf < 4; ++mf)
    #pragma unroll
    for (int rg = 0; rg < 4; ++rg){
      sv1[mf][rg] = 3.4e38f; sv2[mf][rg] = 3.4e38f;
      si1[mf][rg] = 0x7fffffff; si2[mf][rg] = 0x7fffffff;
    }

  f32x4_t acc[4][2];
  #pragma unroll
  for (int mf = 0; mf < 4; ++mf)
    #pragma unroll
    for (int cf = 0; cf < 2; ++cf){
      f32x4_t z = {0.f,0.f,0.f,0.f};
      acc[mf][cf] = z;
    }

  // B staging pattern: code = tid>>1 (0..127), cHalf = (tid&1)*16
  const int codeS = tid >> 1;
  const int cHalf = (tid & 1) << 4;

  // prologue: load iteration 0's B chunk (kt=0, cc=0)
  float4 rb0, rb1, rb2, rb3;
  {
    const float* cp = cb + (size_t)codeS * DIMS + cHalf;
    rb0 = *(const float4*)(cp);
    rb1 = *(const float4*)(cp + 4);
    rb2 = *(const float4*)(cp + 8);
    rb3 = *(const float4*)(cp + 12);
  }

  for (int it = 0; it < 64; ++it){
    const int kt = it >> 3;
    const int cc = it & 7;
    const int s  = it & 1;

    // convert + write current B chunk (scaled x512, exact pow2)
    {
      f16x4_t p;
      p.x=(_Float16)(rb0.x*512.f); p.y=(_Float16)(rb0.y*512.f);
      p.z=(_Float16)(rb0.z*512.f); p.w=(_Float16)(rb0.w*512.f);
      *(f16x4_t*)&Bh[s][codeS][cHalf + 0] = p;
      p.x=(_Float16)(rb1.x*512.f); p.y=(_Float16)(rb1.y*512.f);
      p.z=(_Float16)(rb1.z*512.f); p.w=(_Float16)(rb1.w*512.f);
      *(f16x4_t*)&Bh[s][codeS][cHalf + 4] = p;
      p.x=(_Float16)(rb2.x*512.f); p.y=(_Float16)(rb2.y*512.f);
      p.z=(_Float16)(rb2.z*512.f); p.w=(_Float16)(rb2.w*512.f);
      *(f16x4_t*)&Bh[s][codeS][cHalf + 8] = p;
      p.x=(_Float16)(rb3.x*512.f); p.y=(_Float16)(rb3.y*512.f);
      p.z=(_Float16)(rb3.z*512.f); p.w=(_Float16)(rb3.w*512.f);
      *(f16x4_t*)&Bh[s][codeS][cHalf + 12] = p;
    }
    // issue next chunk's loads (one iteration of latency slack)
    if (it < 63){
      const int nkt = (it + 1) >> 3, ncc = (it + 1) & 7;
      const float* cp = cb + (size_t)(nkt*128 + codeS) * DIMS + ncc*32 + cHalf;
      rb0 = *(const float4*)(cp);
      rb1 = *(const float4*)(cp + 4);
      rb2 = *(const float4*)(cp + 8);
      rb3 = *(const float4*)(cp + 12);
    }

    __syncthreads();   // B[s] writes visible; prev iteration's reads of B[s^1] already done

    f16x8_t bhf[2];
    #pragma unroll
    for (int cf = 0; cf < 2; ++cf)
      bhf[cf] = *(const f16x8_t*)&Bh[s][wc*32 + cf*16 + fr][fq*8];
    #pragma unroll
    for (int mf = 0; mf < 4; ++mf){
      f16x8_t ahf = *(const f16x8_t*)&Ah[mf*16 + fr][cc*32 + fq*8];
      acc[mf][0] = __builtin_amdgcn_mfma_f32_16x16x32_f16(ahf, bhf[0], acc[mf][0], 0, 0, 0);
      acc[mf][1] = __builtin_amdgcn_mfma_f32_16x16x32_f16(ahf, bhf[1], acc[mf][1], 0, 0, 0);
    }

    if (cc == 7){
      // fold this kt's 32 codes into the running top-2 (per thread; no shuffles)
      float sev0 = se[kt*128 + wc*32 + 0*16 + fr];
      float sev1 = se[kt*128 + wc*32 + 1*16 + fr];
      #pragma unroll
      for (int mf = 0; mf < 4; ++mf){
        #pragma unroll
        for (int rg = 0; rg < 4; ++rg){
          float v0 = fmaf(acc[mf][0][rg], -1.0f/256.0f, sev0);
          float v1 = fmaf(acc[mf][1][rg], -1.0f/256.0f, sev1);
          int ci0 = kt*128 + wc*32 + fr;
          t2ins(v0, ci0,      sv1[mf][rg], si1[mf][rg], sv2[mf][rg], si2[mf][rg]);
          t2ins(v1, ci0 + 16, sv1[mf][rg], si1[mf][rg], sv2[mf][rg], si2[mf][rg]);
        }
        f32x4_t z = {0.f,0.f,0.f,0.f};
        acc[mf][0] = z; acc[mf][1] = z;
      }
    }
  }

  // ---- deferred cross-lane reduce (over fr within each fq group) ----
  #pragma unroll
  for (int mf = 0; mf < 4; ++mf){
    #pragma unroll
    for (int rg = 0; rg < 4; ++rg){
      float v1 = sv1[mf][rg], v2 = sv2[mf][rg];
      int   i1 = si1[mf][rg], i2 = si2[mf][rg];
      #pragma unroll
      for (int m = 1; m < 16; m <<= 1){
        float ov1 = __shfl_xor(v1, m);
        int   oi1 = __shfl_xor(i1, m);
        float ov2 = __shfl_xor(v2, m);
        int   oi2 = __shfl_xor(i2, m);
        t2ins(ov1, oi1, v1, i1, v2, i2);
        t2ins(ov2, oi2, v1, i1, v2, i2);
      }
      if (fr == 0)
        comb[mf*16 + fq*4 + rg][wc] = make_float4(v1, __int_as_float(i1), v2, __int_as_float(i2));
    }
  }
  __syncthreads();
  if (tid < 64){
    float v1 = 3.4e38f, v2 = 3.4e38f;
    int   i1 = 0x7fffffff, i2 = 0x7fffffff;
    #pragma unroll
    for (int w = 0; w < 4; ++w){
      float4 p = comb[tid][w];
      t2ins(p.x, __float_as_int(p.y), v1, i1, v2, i2);
      t2ins(p.z, __float_as_int(p.w), v1, i1, v2, i2);
    }
    const int r = n0 + tid;
    idx[r]  = i1;
    out2[r] = (float)i1;
    if (!(v2 - v1 >= THETA)){
      unsigned pos = atomicAdd(cnt, 1u);
      wl[pos] = (unsigned)r;
    }
  }
}

// ---- kernel 3: exact fp32-numpy-emulated full re-scan of flagged rows (8 rows/block) ----
__global__ __launch_bounds__(256) void vq_refine(
    const float* __restrict__ x, const float* __restrict__ cb,
    const float* __restrict__ sx, const float* __restrict__ se,
    const unsigned* __restrict__ wl, const unsigned* __restrict__ cnt,
    int* __restrict__ idx, float* __restrict__ out2)
{
  __shared__ float eT[8][1024];   // 32 KiB transposed codebook chunk
  __shared__ float xs[DIMS][8];   // 8 KiB
  __shared__ int   rows_s[8];
  __shared__ float sxs[8];
  __shared__ float wv[4][8];
  __shared__ int   wi[4][8];

  const unsigned n = *cnt;
  const unsigned groups = (n + 7u) >> 3;
  const int tid  = threadIdx.x;
  const int lane = tid & 63;
  const int wid  = tid >> 6;

  for (unsigned g = blockIdx.x; g < groups; g += gridDim.x){
    __syncthreads();   // protect rows_s/xs/wv reuse across groups
    if (tid < 8){
      unsigned e = g*8u + (unsigned)tid;
      int row = (int)wl[e < n ? e : (n - 1u)];
      rows_s[tid] = row;
      sxs[tid] = sx[row];
    }
    __syncthreads();
    // stage x rows (scattered gather along c)
    #pragma unroll
    for (int rep = 0; rep < 8; ++rep){
      int id = rep * 256 + tid;
      int c = id >> 3, r = id & 7;
      int row = rows_s[r];
      int b = row >> 12, t = row & 4095;
      xs[c][r] = x[((size_t)(b*DIMS + c))*NT + t];
    }

    float s[8][4];
    #pragma unroll
    for (int r = 0; r < 8; ++r)
      #pragma unroll
      for (int u = 0; u < 4; ++u) s[r][u] = 0.f;

    for (int c0 = 0; c0 < DIMS; c0 += 8){
      __syncthreads();
      #pragma unroll
      for (int rep = 0; rep < 8; ++rep){
        int id2 = rep * 256 + tid;
        int k = id2 >> 1, q = id2 & 1;
        float4 v = *(const float4*)&cb[(size_t)k * DIMS + c0 + q * 4];
        eT[q*4 + 0][k] = v.x; eT[q*4 + 1][k] = v.y;
        eT[q*4 + 2][k] = v.z; eT[q*4 + 3][k] = v.w;
      }
      __syncthreads();
      #pragma unroll
      for (int cc = 0; cc < 8; ++cc){
        float4 ev = *(const float4*)&eT[cc][wid*256 + lane*4];
        #pragma unroll
        for (int r = 0; r < 8; ++r){
          float xv = xs[c0 + cc][r];
          s[r][0] = fmaf(xv, ev.x, s[r][0]);
          s[r][1] = fmaf(xv, ev.y, s[r][1]);
          s[r][2] = fmaf(xv, ev.z, s[r][2]);
          s[r][3] = fmaf(xv, ev.w, s[r][3]);
        }
      }
    }

    float4 sek = *(const float4*)&se[wid*256 + lane*4];
    #pragma unroll
    for (int r = 0; r < 8; ++r){
      const float sxv = sxs[r];
      float bv = 3.4e38f; int bi = 0x7fffffff;
      #pragma unroll
      for (int u = 0; u < 4; ++u){
        float d = __fsub_rn(__fadd_rn(sxv, (&sek.x)[u]),
                            __fadd_rn(s[r][u], s[r][u]));
        int k = wid*256 + lane*4 + u;
        if (d < bv || (d == bv && k < bi)) { bv = d; bi = k; }
      }
      #pragma unroll
      for (int m = 1; m < 64; m <<= 1){
        float ov = __shfl_xor(bv, m);
        int   oi = __shfl_xor(bi, m);
        if (ov < bv || (ov == bv && oi < bi)) { bv = ov; bi = oi; }
      }
      if (lane == 0){ wv[wid][r] = bv; wi[wid][r] = bi; }
    }
    __syncthreads();
    if (tid < 8){
      const int r = tid;
      float bv = wv[0][r]; int bi = wi[0][r];
      #pragma unroll
      for (int w = 1; w < 4; ++w){
        float ov = wv[w][r]; int oi = wi[w][r];
        if (ov < bv || (ov == bv && oi < bi)) { bv = ov; bi = oi; }
      }
      if (g*8u + (unsigned)r < n){
        int row = rows_s[r];
        idx[row]  = bi;
        out2[row] = (float)bi;
      }
    }
  }
}

// ---- kernel 4: gather quantized (== quantized_st), accumulate loss ----
__global__ __launch_bounds__(256) void vq_gather(
    const float* __restrict__ x, const float* __restrict__ cb,
    const int* __restrict__ idx, float* __restrict__ out0, double* __restrict__ acc)
{
  const int bc = blockIdx.x;          // b*256 + c
  const int bb = bc >> 8;
  const int c  = bc & 255;
  const float* xr = x + (size_t)bc * NT;
  float* orow = out0 + (size_t)bc * NT;
  const int* ir = idx + bb * NT;
  float s = 0.f;
  #pragma unroll
  for (int j = 0; j < 4; ++j){
    const int t = (threadIdx.x << 2) + (j << 10);
    float4 xv = *(const float4*)(xr + t);
    int4  iv  = *(const int4*)(ir + t);
    float4 q;
    q.x = cb[iv.x * DIMS + c];
    q.y = cb[iv.y * DIMS + c];
    q.z = cb[iv.z * DIMS + c];
    q.w = cb[iv.w * DIMS + c];
    float dx = q.x - xv.x, dy = q.y - xv.y, dz = q.z - xv.z, dw = q.w - xv.w;
    s += dx*dx + dy*dy + dz*dz + dw*dw;
    *(float4*)(orow + t) = q;
  }
  #pragma unroll
  for (int m = 1; m < 64; m <<= 1) s += __shfl_xor(s, m);
  __shared__ float wsum[4];
  if ((threadIdx.x & 63) == 0) wsum[threadIdx.x >> 6] = s;
  __syncthreads();
  if (threadIdx.x == 0){
    double tot = (double)wsum[0] + (double)wsum[1] + (double)wsum[2] + (double)wsum[3];
    atomicAdd(acc, tot);
  }
}

__global__ void vq_final(const double* __restrict__ acc, float* __restrict__ out1){
  *out1 = (float)(1.25 * (*acc) * (1.0 / 16777216.0));
}

extern "C" void kernel_launch(void* const* d_in, const int* in_sizes, int n_in,
                              void* d_out, int out_size, void* d_ws, size_t ws_size,
                              hipStream_t stream)
{
  const float* x  = (const float*)d_in[0];
  const float* cb = (const float*)d_in[1];
  float* out  = (float*)d_out;
  float* out0 = out;
  float* out1 = out + (size_t)16777216;   // vq_loss
  float* out2 = out + (size_t)16777217;   // indices as float [65536]

  char* ws = (char*)d_ws;
  double*   acc = (double*)(ws + 0);
  unsigned* cnt = (unsigned*)(ws + 8);
  float*    se  = (float*)(ws + 64);       // 4 KiB
  float*    sx  = (float*)(ws + 4160);     // 256 KiB
  int*      idx = (int*)(ws + 266304);     // 256 KiB

  // worklist lives in the out0 region (overwritten later by vq_gather):
  unsigned* wl = (unsigned*)(out + (size_t)4*1024*1024);   // at 16 MiB, 256 KiB

  hipMemsetAsync(d_ws, 0, 16, stream);     // zero loss accumulator + worklist count
  vq_sx    <<<dim3(256),  dim3(256), 0, stream>>>(x, sx);
  vq_se    <<<dim3(16),   dim3(64),  0, stream>>>(cb, se);
  vq_scores<<<dim3(1024), dim3(256), 0, stream>>>(x, cb, se, idx, out2, wl, cnt);
  vq_refine<<<dim3(512),  dim3(256), 0, stream>>>(x, cb, sx, se, wl, cnt, idx, out2);
  vq_gather<<<dim3(4096), dim3(256), 0, stream>>>(x, cb, idx, out0, acc);
  vq_final <<<dim3(1),    dim3(1),   0, stream>>>(acc, out1);
}

// Round 6
// 721.605 us; speedup vs baseline: 1.1746x; 1.0762x over previous
//
#include <hip/hip_runtime.h>
#include <stdint.h>

#define DIMS 256
#define NT 4096
#define NROWS 65536
#define THETA 1.5e-4f

typedef float    f32x4_t __attribute__((ext_vector_type(4)));
typedef _Float16 f16x8_t __attribute__((ext_vector_type(8)));
typedef _Float16 f16x4_t __attribute__((ext_vector_type(4)));

// top-2 insert with jnp.argmin tie-break (lowest index wins on equal value)
__device__ __forceinline__ void t2ins(float v, int i, float& v1, int& i1, float& v2, int& i2){
  if (v < v1 || (v == v1 && i < i1)) { v2 = v1; i2 = i1; v1 = v; i1 = i; }
  else if (v < v2 || (v == v2 && i < i2)) { v2 = v; i2 = i; }
}

// ---- kernel 0a: sx[n] = np.sum(flat*flat, axis=1) bit-exact (pairwise 256 = P128 + P128) ----
__global__ __launch_bounds__(256) void vq_sx(const float* __restrict__ x, float* __restrict__ sx){
  const int n = blockIdx.x * 256 + threadIdx.x;
  const int b = n >> 12, t = n & 4095;
  const float* xp = x + (size_t)b * DIMS * NT + t;
  float half[2];
  #pragma unroll
  for (int h = 0; h < 2; ++h){
    float r[8];
    #pragma unroll
    for (int j = 0; j < 8; ++j){
      float v = xp[(size_t)(h*128 + j) * NT];
      r[j] = __fmul_rn(v, v);
    }
    for (int i = 8; i < 128; i += 8){
      #pragma unroll
      for (int j = 0; j < 8; ++j){
        float v = xp[(size_t)(h*128 + i + j) * NT];
        r[j] = __fadd_rn(r[j], __fmul_rn(v, v));
      }
    }
    half[h] = __fadd_rn(__fadd_rn(__fadd_rn(r[0], r[1]), __fadd_rn(r[2], r[3])),
                        __fadd_rn(__fadd_rn(r[4], r[5]), __fadd_rn(r[6], r[7])));
  }
  sx[n] = __fadd_rn(half[0], half[1]);
}

// ---- kernel 0b: se[k] = np.sum(cb*cb, axis=1) bit-exact ----
__global__ void vq_se(const float* __restrict__ cb, float* __restrict__ se){
  const int k = blockIdx.x * 64 + threadIdx.x;
  const float* ep = cb + (size_t)k * DIMS;
  float half[2];
  #pragma unroll
  for (int h = 0; h < 2; ++h){
    float r[8];
    #pragma unroll
    for (int j = 0; j < 8; ++j){
      float v = ep[h*128 + j];
      r[j] = __fmul_rn(v, v);
    }
    for (int i = 8; i < 128; i += 8){
      #pragma unroll
      for (int j = 0; j < 8; ++j){
        float v = ep[h*128 + i + j];
        r[j] = __fadd_rn(r[j], __fmul_rn(v, v));
      }
    }
    half[h] = __fadd_rn(__fadd_rn(__fadd_rn(r[0], r[1]), __fadd_rn(r[2], r[3])),
                        __fadd_rn(__fadd_rn(r[4], r[5]), __fadd_rn(r[6], r[7])));
  }
  se[k] = __fadd_rn(half[0], half[1]);
}

// ---- kernel 0c: cb16[k][c] = (_Float16)(cb[k][c] * 512) once (pure-pow2 scale) ----
__global__ __launch_bounds__(256) void vq_cvt(const float* __restrict__ cb, _Float16* __restrict__ cb16){
  const int i = (blockIdx.x * 256 + threadIdx.x) * 4;
  float4 v = *(const float4*)(cb + i);
  f16x4_t p;
  p.x = (_Float16)(v.x * 512.f);
  p.y = (_Float16)(v.y * 512.f);
  p.z = (_Float16)(v.z * 512.f);
  p.w = (_Float16)(v.w * 512.f);
  *(f16x4_t*)(cb16 + i) = p;
}

// ---- kernel 1: approx scores, 64 rows/block x ALL 1024 codes, fused top-2 ----
// A (x tile) staged once in LDS fp16; B = preconverted fp16 codebook, double-buffered
// 16KB chunks (256 codes x 32 c). score = se_k - dot/256. 2 waves/EU: no spills.
__global__ __launch_bounds__(256, 2) void vq_scores(
    const float* __restrict__ x, const _Float16* __restrict__ cb16,
    const float* __restrict__ se, int* __restrict__ idx, float* __restrict__ out2,
    unsigned* __restrict__ wl, unsigned* __restrict__ cnt)
{
  __shared__ _Float16 Ah[64][264];        // 33792 B, row stride 132 dw === 4 (mod 32)
  __shared__ _Float16 Bh[2][256][40];     // 40960 B
  __shared__ float4   comb[64][4];        //  4096 B

  const int tid  = threadIdx.x;
  const int lane = tid & 63;
  const int wc   = tid >> 6;              // wave -> 64-code stripe within 256-code kt tile
  const int fr   = lane & 15;
  const int fq   = lane >> 4;
  const int n0   = blockIdx.x * 64;
  const int bb   = n0 >> 12;
  const int t0   = n0 & 4095;

  // ---- stage A once: 64 rows x 256 c, fp16 ----
  {
    const int dup = tid >> 7;                 // 0..1 -> c chunks 0-3 / 4-7
    const int c4  = tid & 7;                  // c quad within chunk
    const int tt  = ((tid >> 3) & 15) << 2;   // 4-row group
    #pragma unroll
    for (int cc2 = 0; cc2 < 4; ++cc2){
      const int c0 = (dup*4 + cc2) * 32;
      const float* xp = x + ((size_t)(bb*DIMS + c0 + c4*4))*NT + t0 + tt;
      float4 va0 = *(const float4*)(xp);
      float4 va1 = *(const float4*)(xp + NT);
      float4 va2 = *(const float4*)(xp + 2*NT);
      float4 va3 = *(const float4*)(xp + 3*NT);
      #pragma unroll
      for (int j = 0; j < 4; ++j){
        f16x4_t p;
        p.x = (_Float16)((&va0.x)[j]);
        p.y = (_Float16)((&va1.x)[j]);
        p.z = (_Float16)((&va2.x)[j]);
        p.w = (_Float16)((&va3.x)[j]);
        *(f16x4_t*)&Ah[tt + j][c0 + c4*4] = p;
      }
    }
  }

  // per-thread running top-2 state per (mf, rg)
  float sv1[4][4], sv2[4][4];
  int   si1[4][4], si2[4][4];
  #pragma unroll
  for (int mf = 0; mf < 4; ++mf)
    #pragma unroll
    for (int rg = 0; rg < 4; ++rg){
      sv1[mf][rg] = 3.4e38f; sv2[mf][rg] = 3.4e38f;
      si1[mf][rg] = 0x7fffffff; si2[mf][rg] = 0x7fffffff;
    }

  f32x4_t acc[4][4];
  #pragma unroll
  for (int mf = 0; mf < 4; ++mf)
    #pragma unroll
    for (int cf = 0; cf < 4; ++cf){
      f32x4_t z = {0.f,0.f,0.f,0.f};
      acc[mf][cf] = z;
    }

  // B staging: one code per thread, 32 c per iteration (4 x 16B copies)
  const int codeS = tid;

  f16x8_t rb[4];
  {
    const _Float16* cp = cb16 + (size_t)codeS * DIMS;   // kt=0, cc=0
    #pragma unroll
    for (int q = 0; q < 4; ++q) rb[q] = *(const f16x8_t*)(cp + q*8);
  }

  for (int it = 0; it < 32; ++it){
    const int kt = it >> 3;
    const int cc = it & 7;
    const int s  = it & 1;

    // write current B chunk to LDS
    #pragma unroll
    for (int q = 0; q < 4; ++q)
      *(f16x8_t*)&Bh[s][codeS][q*8] = rb[q];

    // issue next chunk's loads (one iteration of latency slack)
    if (it < 31){
      const int nkt = (it + 1) >> 3, ncc = (it + 1) & 7;
      const _Float16* cp = cb16 + (size_t)(nkt*256 + codeS) * DIMS + ncc*32;
      #pragma unroll
      for (int q = 0; q < 4; ++q) rb[q] = *(const f16x8_t*)(cp + q*8);
    }

    __syncthreads();   // B[s] writes visible; prior reads of B[s^1] already done

    f16x8_t bhf[4];
    #pragma unroll
    for (int cf = 0; cf < 4; ++cf)
      bhf[cf] = *(const f16x8_t*)&Bh[s][wc*64 + cf*16 + fr][fq*8];
    #pragma unroll
    for (int mf = 0; mf < 4; ++mf){
      f16x8_t ahf = *(const f16x8_t*)&Ah[mf*16 + fr][cc*32 + fq*8];
      #pragma unroll
      for (int cf = 0; cf < 4; ++cf)
        acc[mf][cf] = __builtin_amdgcn_mfma_f32_16x16x32_f16(ahf, bhf[cf], acc[mf][cf], 0, 0, 0);
    }

    if (cc == 7){
      // fold this kt's 64 codes (per thread: 4 cf x this lane's fr) into running top-2
      float sev[4];
      #pragma unroll
      for (int cf = 0; cf < 4; ++cf) sev[cf] = se[kt*256 + wc*64 + cf*16 + fr];
      #pragma unroll
      for (int mf = 0; mf < 4; ++mf){
        #pragma unroll
        for (int rg = 0; rg < 4; ++rg){
          #pragma unroll
          for (int cf = 0; cf < 4; ++cf){
            float v = fmaf(acc[mf][cf][rg], -1.0f/256.0f, sev[cf]);
            int  ci = kt*256 + wc*64 + cf*16 + fr;
            t2ins(v, ci, sv1[mf][rg], si1[mf][rg], sv2[mf][rg], si2[mf][rg]);
          }
        }
        #pragma unroll
        for (int cf = 0; cf < 4; ++cf){
          f32x4_t z = {0.f,0.f,0.f,0.f};
          acc[mf][cf] = z;
        }
      }
    }
  }

  // ---- deferred cross-lane reduce (over fr within each fq group) ----
  #pragma unroll
  for (int mf = 0; mf < 4; ++mf){
    #pragma unroll
    for (int rg = 0; rg < 4; ++rg){
      float v1 = sv1[mf][rg], v2 = sv2[mf][rg];
      int   i1 = si1[mf][rg], i2 = si2[mf][rg];
      #pragma unroll
      for (int m = 1; m < 16; m <<= 1){
        float ov1 = __shfl_xor(v1, m);
        int   oi1 = __shfl_xor(i1, m);
        float ov2 = __shfl_xor(v2, m);
        int   oi2 = __shfl_xor(i2, m);
        t2ins(ov1, oi1, v1, i1, v2, i2);
        t2ins(ov2, oi2, v1, i1, v2, i2);
      }
      if (fr == 0)
        comb[mf*16 + fq*4 + rg][wc] = make_float4(v1, __int_as_float(i1), v2, __int_as_float(i2));
    }
  }
  __syncthreads();
  if (tid < 64){
    float v1 = 3.4e38f, v2 = 3.4e38f;
    int   i1 = 0x7fffffff, i2 = 0x7fffffff;
    #pragma unroll
    for (int w = 0; w < 4; ++w){
      float4 p = comb[tid][w];
      t2ins(p.x, __float_as_int(p.y), v1, i1, v2, i2);
      t2ins(p.z, __float_as_int(p.w), v1, i1, v2, i2);
    }
    const int r = n0 + tid;
    idx[r]  = i1;
    out2[r] = (float)i1;
    if (!(v2 - v1 >= THETA)){
      unsigned pos = atomicAdd(cnt, 1u);
      wl[pos] = (unsigned)r;
    }
  }
}

// ---- kernel 3: exact fp32-numpy-emulated full re-scan of flagged rows (8 rows/block) ----
__global__ __launch_bounds__(256) void vq_refine(
    const float* __restrict__ x, const float* __restrict__ cb,
    const float* __restrict__ sx, const float* __restrict__ se,
    const unsigned* __restrict__ wl, const unsigned* __restrict__ cnt,
    int* __restrict__ idx, float* __restrict__ out2)
{
  __shared__ float eT[8][1024];   // 32 KiB transposed codebook chunk
  __shared__ float xs[DIMS][8];   // 8 KiB
  __shared__ int   rows_s[8];
  __shared__ float sxs[8];
  __shared__ float wv[4][8];
  __shared__ int   wi[4][8];

  const unsigned n = *cnt;
  const unsigned groups = (n + 7u) >> 3;
  const int tid  = threadIdx.x;
  const int lane = tid & 63;
  const int wid  = tid >> 6;

  for (unsigned g = blockIdx.x; g < groups; g += gridDim.x){
    __syncthreads();   // protect rows_s/xs/wv reuse across groups
    if (tid < 8){
      unsigned e = g*8u + (unsigned)tid;
      int row = (int)wl[e < n ? e : (n - 1u)];
      rows_s[tid] = row;
      sxs[tid] = sx[row];
    }
    __syncthreads();
    // stage x rows (scattered gather along c)
    #pragma unroll
    for (int rep = 0; rep < 8; ++rep){
      int id = rep * 256 + tid;
      int c = id >> 3, r = id & 7;
      int row = rows_s[r];
      int b = row >> 12, t = row & 4095;
      xs[c][r] = x[((size_t)(b*DIMS + c))*NT + t];
    }

    float s[8][4];
    #pragma unroll
    for (int r = 0; r < 8; ++r)
      #pragma unroll
      for (int u = 0; u < 4; ++u) s[r][u] = 0.f;

    for (int c0 = 0; c0 < DIMS; c0 += 8){
      __syncthreads();
      #pragma unroll
      for (int rep = 0; rep < 8; ++rep){
        int id2 = rep * 256 + tid;
        int k = id2 >> 1, q = id2 & 1;
        float4 v = *(const float4*)&cb[(size_t)k * DIMS + c0 + q * 4];
        eT[q*4 + 0][k] = v.x; eT[q*4 + 1][k] = v.y;
        eT[q*4 + 2][k] = v.z; eT[q*4 + 3][k] = v.w;
      }
      __syncthreads();
      #pragma unroll
      for (int cc = 0; cc < 8; ++cc){
        float4 ev = *(const float4*)&eT[cc][wid*256 + lane*4];
        #pragma unroll
        for (int r = 0; r < 8; ++r){
          float xv = xs[c0 + cc][r];
          s[r][0] = fmaf(xv, ev.x, s[r][0]);
          s[r][1] = fmaf(xv, ev.y, s[r][1]);
          s[r][2] = fmaf(xv, ev.z, s[r][2]);
          s[r][3] = fmaf(xv, ev.w, s[r][3]);
        }
      }
    }

    float4 sek = *(const float4*)&se[wid*256 + lane*4];
    #pragma unroll
    for (int r = 0; r < 8; ++r){
      const float sxv = sxs[r];
      float bv = 3.4e38f; int bi = 0x7fffffff;
      #pragma unroll
      for (int u = 0; u < 4; ++u){
        float d = __fsub_rn(__fadd_rn(sxv, (&sek.x)[u]),
                            __fadd_rn(s[r][u], s[r][u]));
        int k = wid*256 + lane*4 + u;
        if (d < bv || (d == bv && k < bi)) { bv = d; bi = k; }
      }
      #pragma unroll
      for (int m = 1; m < 64; m <<= 1){
        float ov = __shfl_xor(bv, m);
        int   oi = __shfl_xor(bi, m);
        if (ov < bv || (ov == bv && oi < bi)) { bv = ov; bi = oi; }
      }
      if (lane == 0){ wv[wid][r] = bv; wi[wid][r] = bi; }
    }
    __syncthreads();
    if (tid < 8){
      const int r = tid;
      float bv = wv[0][r]; int bi = wi[0][r];
      #pragma unroll
      for (int w = 1; w < 4; ++w){
        float ov = wv[w][r]; int oi = wi[w][r];
        if (ov < bv || (ov == bv && oi < bi)) { bv = ov; bi = oi; }
      }
      if (g*8u + (unsigned)r < n){
        int row = rows_s[r];
        idx[row]  = bi;
        out2[row] = (float)bi;
      }
    }
  }
}

// ---- kernel 4: gather quantized (== quantized_st), accumulate loss ----
__global__ __launch_bounds__(256) void vq_gather(
    const float* __restrict__ x, const float* __restrict__ cb,
    const int* __restrict__ idx, float* __restrict__ out0, double* __restrict__ acc)
{
  const int bc = blockIdx.x;          // b*256 + c
  const int bb = bc >> 8;
  const int c  = bc & 255;
  const float* xr = x + (size_t)bc * NT;
  float* orow = out0 + (size_t)bc * NT;
  const int* ir = idx + bb * NT;
  float s = 0.f;
  #pragma unroll
  for (int j = 0; j < 4; ++j){
    const int t = (threadIdx.x << 2) + (j << 10);
    float4 xv = *(const float4*)(xr + t);
    int4  iv  = *(const int4*)(ir + t);
    float4 q;
    q.x = cb[iv.x * DIMS + c];
    q.y = cb[iv.y * DIMS + c];
    q.z = cb[iv.z * DIMS + c];
    q.w = cb[iv.w * DIMS + c];
    float dx = q.x - xv.x, dy = q.y - xv.y, dz = q.z - xv.z, dw = q.w - xv.w;
    s += dx*dx + dy*dy + dz*dz + dw*dw;
    *(float4*)(orow + t) = q;
  }
  #pragma unroll
  for (int m = 1; m < 64; m <<= 1) s += __shfl_xor(s, m);
  __shared__ float wsum[4];
  if ((threadIdx.x & 63) == 0) wsum[threadIdx.x >> 6] = s;
  __syncthreads();
  if (threadIdx.x == 0){
    double tot = (double)wsum[0] + (double)wsum[1] + (double)wsum[2] + (double)wsum[3];
    atomicAdd(acc, tot);
  }
}

__global__ void vq_final(const double* __restrict__ acc, float* __restrict__ out1){
  *out1 = (float)(1.25 * (*acc) * (1.0 / 16777216.0));
}

extern "C" void kernel_launch(void* const* d_in, const int* in_sizes, int n_in,
                              void* d_out, int out_size, void* d_ws, size_t ws_size,
                              hipStream_t stream)
{
  const float* x  = (const float*)d_in[0];
  const float* cb = (const float*)d_in[1];
  float* out  = (float*)d_out;
  float* out0 = out;
  float* out1 = out + (size_t)16777216;   // vq_loss
  float* out2 = out + (size_t)16777217;   // indices as float [65536]

  char* ws = (char*)d_ws;
  double*   acc  = (double*)(ws + 0);
  unsigned* cnt  = (unsigned*)(ws + 8);
  float*    se   = (float*)(ws + 64);       // 4 KiB
  float*    sx   = (float*)(ws + 4160);     // 256 KiB
  int*      idx  = (int*)(ws + 266304);     // 256 KiB
  _Float16* cb16 = (_Float16*)(ws + 528448);// 512 KiB fp16 codebook (x512)

  // worklist lives in the out0 region (overwritten later by vq_gather):
  unsigned* wl = (unsigned*)(out + (size_t)4*1024*1024);   // at 16 MiB, 256 KiB

  hipMemsetAsync(d_ws, 0, 16, stream);     // zero loss accumulator + worklist count
  vq_sx    <<<dim3(256),  dim3(256), 0, stream>>>(x, sx);
  vq_se    <<<dim3(16),   dim3(64),  0, stream>>>(cb, se);
  vq_cvt   <<<dim3(256),  dim3(256), 0, stream>>>(cb, cb16);
  vq_scores<<<dim3(1024), dim3(256), 0, stream>>>(x, cb16, se, idx, out2, wl, cnt);
  vq_refine<<<dim3(512),  dim3(256), 0, stream>>>(x, cb, sx, se, wl, cnt, idx, out2);
  vq_gather<<<dim3(4096), dim3(256), 0, stream>>>(x, cb, idx, out0, acc);
  vq_final <<<dim3(1),    dim3(1),   0, stream>>>(acc, out1);
}

// Round 7
// 243.968 us; speedup vs baseline: 3.4743x; 2.9578x over previous
//
#include <hip/hip_runtime.h>
#include <stdint.h>

#define DIMS 256
#define NT 4096
#define NROWS 65536
#define THETA 1.5e-4f

typedef float    f32x4_t __attribute__((ext_vector_type(4)));
typedef _Float16 f16x8_t __attribute__((ext_vector_type(8)));
typedef _Float16 f16x4_t __attribute__((ext_vector_type(4)));

// ---- kernel 0a: sx[n] = np.sum(flat*flat, axis=1) bit-exact (pairwise 256 = P128 + P128) ----
__global__ __launch_bounds__(256) void vq_sx(const float* __restrict__ x, float* __restrict__ sx){
  const int n = blockIdx.x * 256 + threadIdx.x;
  const int b = n >> 12, t = n & 4095;
  const float* xp = x + (size_t)b * DIMS * NT + t;
  float half[2];
  #pragma unroll
  for (int h = 0; h < 2; ++h){
    float r[8];
    #pragma unroll
    for (int j = 0; j < 8; ++j){
      float v = xp[(size_t)(h*128 + j) * NT];
      r[j] = __fmul_rn(v, v);
    }
    for (int i = 8; i < 128; i += 8){
      #pragma unroll
      for (int j = 0; j < 8; ++j){
        float v = xp[(size_t)(h*128 + i + j) * NT];
        r[j] = __fadd_rn(r[j], __fmul_rn(v, v));
      }
    }
    half[h] = __fadd_rn(__fadd_rn(__fadd_rn(r[0], r[1]), __fadd_rn(r[2], r[3])),
                        __fadd_rn(__fadd_rn(r[4], r[5]), __fadd_rn(r[6], r[7])));
  }
  sx[n] = __fadd_rn(half[0], half[1]);
}

// ---- kernel 0b: se[k] = np.sum(cb*cb, axis=1) bit-exact ----
__global__ void vq_se(const float* __restrict__ cb, float* __restrict__ se){
  const int k = blockIdx.x * 64 + threadIdx.x;
  const float* ep = cb + (size_t)k * DIMS;
  float half[2];
  #pragma unroll
  for (int h = 0; h < 2; ++h){
    float r[8];
    #pragma unroll
    for (int j = 0; j < 8; ++j){
      float v = ep[h*128 + j];
      r[j] = __fmul_rn(v, v);
    }
    for (int i = 8; i < 128; i += 8){
      #pragma unroll
      for (int j = 0; j < 8; ++j){
        float v = ep[h*128 + i + j];
        r[j] = __fadd_rn(r[j], __fmul_rn(v, v));
      }
    }
    half[h] = __fadd_rn(__fadd_rn(__fadd_rn(r[0], r[1]), __fadd_rn(r[2], r[3])),
                        __fadd_rn(__fadd_rn(r[4], r[5]), __fadd_rn(r[6], r[7])));
  }
  se[k] = __fadd_rn(half[0], half[1]);
}

// ---- kernel 0c: cb16[k][c] = (_Float16)(cb[k][c] * 512) once (pure-pow2 scale) ----
__global__ __launch_bounds__(256) void vq_cvt(const float* __restrict__ cb, _Float16* __restrict__ cb16){
  const int i = (blockIdx.x * 256 + threadIdx.x) * 4;
  float4 v = *(const float4*)(cb + i);
  f16x4_t p;
  p.x = (_Float16)(v.x * 512.f);
  p.y = (_Float16)(v.y * 512.f);
  p.z = (_Float16)(v.z * 512.f);
  p.w = (_Float16)(v.w * 512.f);
  *(f16x4_t*)(cb16 + i) = p;
}

// ================= kernel 1: approx scores, all state in NAMED registers =================
// 64 rows/block x 1024 codes; kt tiles of 256 codes; score = se_k - dot/256.
// Top-2 tracks (best value, best index, second value) only — ties flag for refine.

#define T2I(v, i, v1, i1, v2) { \
  bool lt = (v) < (v1); \
  (v2) = lt ? (v1) : fminf((v2), (v)); \
  (i1) = lt ? (i) : (i1); \
  (v1) = lt ? (v) : (v1); }

#define DECL_T2(M,R) \
  float b1_##M##R = 3.4e38f, b2_##M##R = 3.4e38f; int bi_##M##R = 0x7fffffff;

#define FOLD(M,R) { \
  float v; \
  v = fmaf(a##M##0[R], NEGI, ec0); T2I(v, kc0, b1_##M##R, bi_##M##R, b2_##M##R); \
  v = fmaf(a##M##1[R], NEGI, ec1); T2I(v, kc1, b1_##M##R, bi_##M##R, b2_##M##R); \
  v = fmaf(a##M##2[R], NEGI, ec2); T2I(v, kc2, b1_##M##R, bi_##M##R, b2_##M##R); \
  v = fmaf(a##M##3[R], NEGI, ec3); T2I(v, kc3, b1_##M##R, bi_##M##R, b2_##M##R); }

#define MFMA_ROW(M, CC) { \
  f16x8_t ah = *(const f16x8_t*)&Ah[(M)*16 + fr][(CC)*32 + fq*8]; \
  a##M##0 = __builtin_amdgcn_mfma_f32_16x16x32_f16(ah, bh0, a##M##0, 0, 0, 0); \
  a##M##1 = __builtin_amdgcn_mfma_f32_16x16x32_f16(ah, bh1, a##M##1, 0, 0, 0); \
  a##M##2 = __builtin_amdgcn_mfma_f32_16x16x32_f16(ah, bh2, a##M##2, 0, 0, 0); \
  a##M##3 = __builtin_amdgcn_mfma_f32_16x16x32_f16(ah, bh3, a##M##3, 0, 0, 0); }

#define CC_STEP(CC) { \
  *(f16x8_t*)&Bh[(CC)&1][codeS][0]  = rb0; \
  *(f16x8_t*)&Bh[(CC)&1][codeS][8]  = rb1; \
  *(f16x8_t*)&Bh[(CC)&1][codeS][16] = rb2; \
  *(f16x8_t*)&Bh[(CC)&1][codeS][24] = rb3; \
  if ((CC) < 7){ \
    const _Float16* cp_ = cpKt + ((CC)+1)*32; \
    rb0 = *(const f16x8_t*)(cp_);      rb1 = *(const f16x8_t*)(cp_ + 8); \
    rb2 = *(const f16x8_t*)(cp_ + 16); rb3 = *(const f16x8_t*)(cp_ + 24); \
  } else if (kt < 3){ \
    const _Float16* cp_ = cpKt + 256*DIMS; \
    rb0 = *(const f16x8_t*)(cp_);      rb1 = *(const f16x8_t*)(cp_ + 8); \
    rb2 = *(const f16x8_t*)(cp_ + 16); rb3 = *(const f16x8_t*)(cp_ + 24); \
  } \
  __syncthreads(); \
  { \
    f16x8_t bh0 = *(const f16x8_t*)&Bh[(CC)&1][bC0][fq*8]; \
    f16x8_t bh1 = *(const f16x8_t*)&Bh[(CC)&1][bC1][fq*8]; \
    f16x8_t bh2 = *(const f16x8_t*)&Bh[(CC)&1][bC2][fq*8]; \
    f16x8_t bh3 = *(const f16x8_t*)&Bh[(CC)&1][bC3][fq*8]; \
    MFMA_ROW(0, CC) MFMA_ROW(1, CC) MFMA_ROW(2, CC) MFMA_ROW(3, CC) \
  } }

#define MSTEP(MK) { \
  float ov1 = __shfl_xor(v1, MK); int oi1 = __shfl_xor(i1, MK); float ov2 = __shfl_xor(v2, MK); \
  bool tk = ov1 < v1; \
  v2 = tk ? fminf(v1, ov2) : fminf(v2, ov1); \
  i1 = tk ? oi1 : i1; \
  v1 = tk ? ov1 : v1; }

#define MERGE(M,R) { \
  float v1 = b1_##M##R, v2 = b2_##M##R; int i1 = bi_##M##R; \
  MSTEP(1) MSTEP(2) MSTEP(4) MSTEP(8) \
  if (fr == 0) comb[(M)*16 + fq*4 + (R)][wc] = make_float4(v1, __int_as_float(i1), v2, 0.f); }

__global__ __launch_bounds__(256, 2) void vq_scores(
    const float* __restrict__ x, const _Float16* __restrict__ cb16,
    const float* __restrict__ se, int* __restrict__ idx, float* __restrict__ out2,
    unsigned* __restrict__ wl, unsigned* __restrict__ cnt)
{
  __shared__ _Float16 Ah[64][264];        // 33792 B, row stride 132 dw === 4 (mod 32)
  __shared__ _Float16 Bh[2][256][40];     // 40960 B
  __shared__ float4   comb[64][4];        //  4096 B

  const int tid  = threadIdx.x;
  const int lane = tid & 63;
  const int wc   = tid >> 6;              // wave -> 64-code stripe within a 256-code kt tile
  const int fr   = lane & 15;
  const int fq   = lane >> 4;
  const int n0   = blockIdx.x * 64;
  const int bb   = n0 >> 12;
  const int t0   = n0 & 4095;
  const float NEGI = -1.0f/256.0f;

  // ---- stage A once: 64 rows x 256 c, fp16 ----
  {
    const int dup = tid >> 7;                 // 0..1 -> c chunks 0-3 / 4-7
    const int c4  = tid & 7;                  // c quad within chunk
    const int tt  = ((tid >> 3) & 15) << 2;   // 4-row group
    #pragma unroll
    for (int cc2 = 0; cc2 < 4; ++cc2){
      const int c0 = (dup*4 + cc2) * 32;
      const float* xp = x + ((size_t)(bb*DIMS + c0 + c4*4))*NT + t0 + tt;
      float4 va0 = *(const float4*)(xp);
      float4 va1 = *(const float4*)(xp + NT);
      float4 va2 = *(const float4*)(xp + 2*NT);
      float4 va3 = *(const float4*)(xp + 3*NT);
      #pragma unroll
      for (int j = 0; j < 4; ++j){
        f16x4_t p;
        p.x = (_Float16)((&va0.x)[j]);
        p.y = (_Float16)((&va1.x)[j]);
        p.z = (_Float16)((&va2.x)[j]);
        p.w = (_Float16)((&va3.x)[j]);
        *(f16x4_t*)&Ah[tt + j][c0 + c4*4] = p;
      }
    }
  }
  // comb init (barrier inside first CC_STEP covers this)
  comb[tid >> 2][tid & 3] = make_float4(3.4e38f, __int_as_float(0x7fffffff), 3.4e38f, 0.f);

  // named accumulators (16 x f32x4)
  const f32x4_t Z = {0.f, 0.f, 0.f, 0.f};
  f32x4_t a00=Z,a01=Z,a02=Z,a03=Z, a10=Z,a11=Z,a12=Z,a13=Z,
          a20=Z,a21=Z,a22=Z,a23=Z, a30=Z,a31=Z,a32=Z,a33=Z;
  // named top-2 state (16 rows per thread)
  DECL_T2(0,0) DECL_T2(0,1) DECL_T2(0,2) DECL_T2(0,3)
  DECL_T2(1,0) DECL_T2(1,1) DECL_T2(1,2) DECL_T2(1,3)
  DECL_T2(2,0) DECL_T2(2,1) DECL_T2(2,2) DECL_T2(2,3)
  DECL_T2(3,0) DECL_T2(3,1) DECL_T2(3,2) DECL_T2(3,3)

  const int codeS = tid;                  // B staging: one code per thread
  const int bC0 = wc*64 + 0*16 + fr;
  const int bC1 = wc*64 + 1*16 + fr;
  const int bC2 = wc*64 + 2*16 + fr;
  const int bC3 = wc*64 + 3*16 + fr;

  f16x8_t rb0, rb1, rb2, rb3;
  {
    const _Float16* cp_ = cb16 + (size_t)codeS * DIMS;   // kt=0, cc=0
    rb0 = *(const f16x8_t*)(cp_);      rb1 = *(const f16x8_t*)(cp_ + 8);
    rb2 = *(const f16x8_t*)(cp_ + 16); rb3 = *(const f16x8_t*)(cp_ + 24);
  }

  for (int kt = 0; kt < 4; ++kt){
    const _Float16* cpKt = cb16 + ((size_t)(kt*256) + codeS) * DIMS;
    CC_STEP(0) CC_STEP(1) CC_STEP(2) CC_STEP(3)
    CC_STEP(4) CC_STEP(5) CC_STEP(6) CC_STEP(7)

    // fold this kt's 64 codes into the running top-2 (all named scalars)
    const int kb  = kt*256 + wc*64 + fr;
    const int kc0 = kb, kc1 = kb + 16, kc2 = kb + 32, kc3 = kb + 48;
    const float ec0 = se[kc0], ec1 = se[kc1], ec2 = se[kc2], ec3 = se[kc3];
    FOLD(0,0) FOLD(0,1) FOLD(0,2) FOLD(0,3)
    FOLD(1,0) FOLD(1,1) FOLD(1,2) FOLD(1,3)
    FOLD(2,0) FOLD(2,1) FOLD(2,2) FOLD(2,3)
    FOLD(3,0) FOLD(3,1) FOLD(3,2) FOLD(3,3)
    a00=Z;a01=Z;a02=Z;a03=Z; a10=Z;a11=Z;a12=Z;a13=Z;
    a20=Z;a21=Z;a22=Z;a23=Z; a30=Z;a31=Z;a32=Z;a33=Z;
  }

  // cross-lane (fr) merge, then cross-wave merge via LDS
  MERGE(0,0) MERGE(0,1) MERGE(0,2) MERGE(0,3)
  MERGE(1,0) MERGE(1,1) MERGE(1,2) MERGE(1,3)
  MERGE(2,0) MERGE(2,1) MERGE(2,2) MERGE(2,3)
  MERGE(3,0) MERGE(3,1) MERGE(3,2) MERGE(3,3)
  __syncthreads();
  if (tid < 64){
    float4 p = comb[tid][0];
    float v1 = p.x, v2 = p.z;
    int   i1 = __float_as_int(p.y);
    #pragma unroll
    for (int w = 1; w < 4; ++w){
      p = comb[tid][w];
      bool tk = p.x < v1;
      v2 = tk ? fminf(v1, p.z) : fminf(v2, p.x);
      i1 = tk ? __float_as_int(p.y) : i1;
      v1 = tk ? p.x : v1;
    }
    const int r = n0 + tid;
    idx[r]  = i1;
    out2[r] = (float)i1;
    if (!(v2 - v1 >= THETA)){
      unsigned pos = atomicAdd(cnt, 1u);
      wl[pos] = (unsigned)r;
    }
  }
}

// ---- kernel 3: exact fp32-numpy-emulated full re-scan of flagged rows (8 rows/block) ----
__global__ __launch_bounds__(256) void vq_refine(
    const float* __restrict__ x, const float* __restrict__ cb,
    const float* __restrict__ sx, const float* __restrict__ se,
    const unsigned* __restrict__ wl, const unsigned* __restrict__ cnt,
    int* __restrict__ idx, float* __restrict__ out2)
{
  __shared__ float eT[8][1024];   // 32 KiB transposed codebook chunk
  __shared__ float xs[DIMS][8];   // 8 KiB
  __shared__ int   rows_s[8];
  __shared__ float sxs[8];
  __shared__ float wv[4][8];
  __shared__ int   wi[4][8];

  const unsigned n = *cnt;
  const unsigned groups = (n + 7u) >> 3;
  const int tid  = threadIdx.x;
  const int lane = tid & 63;
  const int wid  = tid >> 6;

  for (unsigned g = blockIdx.x; g < groups; g += gridDim.x){
    __syncthreads();   // protect rows_s/xs/wv reuse across groups
    if (tid < 8){
      unsigned e = g*8u + (unsigned)tid;
      int row = (int)wl[e < n ? e : (n - 1u)];
      rows_s[tid] = row;
      sxs[tid] = sx[row];
    }
    __syncthreads();
    // stage x rows (scattered gather along c)
    #pragma unroll
    for (int rep = 0; rep < 8; ++rep){
      int id = rep * 256 + tid;
      int c = id >> 3, r = id & 7;
      int row = rows_s[r];
      int b = row >> 12, t = row & 4095;
      xs[c][r] = x[((size_t)(b*DIMS + c))*NT + t];
    }

    float s[8][4];
    #pragma unroll
    for (int r = 0; r < 8; ++r)
      #pragma unroll
      for (int u = 0; u < 4; ++u) s[r][u] = 0.f;

    for (int c0 = 0; c0 < DIMS; c0 += 8){
      __syncthreads();
      #pragma unroll
      for (int rep = 0; rep < 8; ++rep){
        int id2 = rep * 256 + tid;
        int k = id2 >> 1, q = id2 & 1;
        float4 v = *(const float4*)&cb[(size_t)k * DIMS + c0 + q * 4];
        eT[q*4 + 0][k] = v.x; eT[q*4 + 1][k] = v.y;
        eT[q*4 + 2][k] = v.z; eT[q*4 + 3][k] = v.w;
      }
      __syncthreads();
      #pragma unroll
      for (int cc = 0; cc < 8; ++cc){
        float4 ev = *(const float4*)&eT[cc][wid*256 + lane*4];
        #pragma unroll
        for (int r = 0; r < 8; ++r){
          float xv = xs[c0 + cc][r];
          s[r][0] = fmaf(xv, ev.x, s[r][0]);
          s[r][1] = fmaf(xv, ev.y, s[r][1]);
          s[r][2] = fmaf(xv, ev.z, s[r][2]);
          s[r][3] = fmaf(xv, ev.w, s[r][3]);
        }
      }
    }

    float4 sek = *(const float4*)&se[wid*256 + lane*4];
    #pragma unroll
    for (int r = 0; r < 8; ++r){
      const float sxv = sxs[r];
      float bv = 3.4e38f; int bi = 0x7fffffff;
      #pragma unroll
      for (int u = 0; u < 4; ++u){
        float d = __fsub_rn(__fadd_rn(sxv, (&sek.x)[u]),
                            __fadd_rn(s[r][u], s[r][u]));
        int k = wid*256 + lane*4 + u;
        if (d < bv || (d == bv && k < bi)) { bv = d; bi = k; }
      }
      #pragma unroll
      for (int m = 1; m < 64; m <<= 1){
        float ov = __shfl_xor(bv, m);
        int   oi = __shfl_xor(bi, m);
        if (ov < bv || (ov == bv && oi < bi)) { bv = ov; bi = oi; }
      }
      if (lane == 0){ wv[wid][r] = bv; wi[wid][r] = bi; }
    }
    __syncthreads();
    if (tid < 8){
      const int r = tid;
      float bv = wv[0][r]; int bi = wi[0][r];
      #pragma unroll
      for (int w = 1; w < 4; ++w){
        float ov = wv[w][r]; int oi = wi[w][r];
        if (ov < bv || (ov == bv && oi < bi)) { bv = ov; bi = oi; }
      }
      if (g*8u + (unsigned)r < n){
        int row = rows_s[r];
        idx[row]  = bi;
        out2[row] = (float)bi;
      }
    }
  }
}

// ---- kernel 4: gather quantized (== quantized_st), accumulate loss ----
__global__ __launch_bounds__(256) void vq_gather(
    const float* __restrict__ x, const float* __restrict__ cb,
    const int* __restrict__ idx, float* __restrict__ out0, double* __restrict__ acc)
{
  const int bc = blockIdx.x;          // b*256 + c
  const int bb = bc >> 8;
  const int c  = bc & 255;
  const float* xr = x + (size_t)bc * NT;
  float* orow = out0 + (size_t)bc * NT;
  const int* ir = idx + bb * NT;
  float s = 0.f;
  #pragma unroll
  for (int j = 0; j < 4; ++j){
    const int t = (threadIdx.x << 2) + (j << 10);
    float4 xv = *(const float4*)(xr + t);
    int4  iv  = *(const int4*)(ir + t);
    float4 q;
    q.x = cb[iv.x * DIMS + c];
    q.y = cb[iv.y * DIMS + c];
    q.z = cb[iv.z * DIMS + c];
    q.w = cb[iv.w * DIMS + c];
    float dx = q.x - xv.x, dy = q.y - xv.y, dz = q.z - xv.z, dw = q.w - xv.w;
    s += dx*dx + dy*dy + dz*dz + dw*dw;
    *(float4*)(orow + t) = q;
  }
  #pragma unroll
  for (int m = 1; m < 64; m <<= 1) s += __shfl_xor(s, m);
  __shared__ float wsum[4];
  if ((threadIdx.x & 63) == 0) wsum[threadIdx.x >> 6] = s;
  __syncthreads();
  if (threadIdx.x == 0){
    double tot = (double)wsum[0] + (double)wsum[1] + (double)wsum[2] + (double)wsum[3];
    atomicAdd(acc, tot);
  }
}

__global__ void vq_final(const double* __restrict__ acc, float* __restrict__ out1){
  *out1 = (float)(1.25 * (*acc) * (1.0 / 16777216.0));
}

extern "C" void kernel_launch(void* const* d_in, const int* in_sizes, int n_in,
                              void* d_out, int out_size, void* d_ws, size_t ws_size,
                              hipStream_t stream)
{
  const float* x  = (const float*)d_in[0];
  const float* cb = (const float*)d_in[1];
  float* out  = (float*)d_out;
  float* out0 = out;
  float* out1 = out + (size_t)16777216;   // vq_loss
  float* out2 = out + (size_t)16777217;   // indices as float [65536]

  char* ws = (char*)d_ws;
  double*   acc  = (double*)(ws + 0);
  unsigned* cnt  = (unsigned*)(ws + 8);
  float*    se   = (float*)(ws + 64);       // 4 KiB
  float*    sx   = (float*)(ws + 4160);     // 256 KiB
  int*      idx  = (int*)(ws + 266304);     // 256 KiB
  _Float16* cb16 = (_Float16*)(ws + 528448);// 512 KiB fp16 codebook (x512)

  // worklist lives in the out0 region (overwritten later by vq_gather):
  unsigned* wl = (unsigned*)(out + (size_t)4*1024*1024);   // at 16 MiB, 256 KiB

  hipMemsetAsync(d_ws, 0, 16, stream);     // zero loss accumulator + worklist count
  vq_sx    <<<dim3(256),  dim3(256), 0, stream>>>(x, sx);
  vq_se    <<<dim3(16),   dim3(64),  0, stream>>>(cb, se);
  vq_cvt   <<<dim3(256),  dim3(256), 0, stream>>>(cb, cb16);
  vq_scores<<<dim3(1024), dim3(256), 0, stream>>>(x, cb16, se, idx, out2, wl, cnt);
  vq_refine<<<dim3(512),  dim3(256), 0, stream>>>(x, cb, sx, se, wl, cnt, idx, out2);
  vq_gather<<<dim3(4096), dim3(256), 0, stream>>>(x, cb, idx, out0, acc);
  vq_final <<<dim3(1),    dim3(1),   0, stream>>>(acc, out1);
}